// Round 4
// baseline (777.651 us; speedup 1.0000x reference)
//
#include <hip/hip_runtime.h>
#include <cstdint>

#define NB 32
#define NN 1000
#define NC 1601
#define HID 64
#define ROWS (NB*NN)       // 32000
#define CAPB 15360         // candidate cap per batch
#define SROWS 15           // sample rows for threshold floor
#define NBIN 4096          // 12-bit key-prefix histogram
#define MSTR 40            // mlp x-plane row stride (bf16), 16B aligned, 2-way banks
#define HSTR 72            // mlp h-plane row stride (bf16)
#define PSTR 40            // score plane row stride (bf16)
#define PPL  (128*PSTR)    // score plane size (ushorts)

typedef short short8 __attribute__((ext_vector_type(8)));
typedef float floatx4 __attribute__((ext_vector_type(4)));

__device__ __forceinline__ uint32_t f2key(float f){
  uint32_t u = __float_as_uint(f);
  return (u & 0x80000000u) ? ~u : (u | 0x80000000u);   // monotone float->uint
}
__device__ __forceinline__ float key2f(uint32_t k){
  uint32_t u = (k & 0x80000000u) ? (k & 0x7fffffffu) : ~k;
  return __uint_as_float(u);
}

// Dekker 3-way bf16 split: v ~= b0 + b1 + b2 exactly to ~2^-24 rel.
__device__ __forceinline__ void split3(float v, ushort& h0, ushort& h1, ushort& h2){
  uint32_t u0 = __float_as_uint(v) & 0xffff0000u;
  h0 = (ushort)(u0 >> 16);
  float r1 = v - __uint_as_float(u0);
  uint32_t u1 = __float_as_uint(r1) & 0xffff0000u;
  h1 = (ushort)(u1 >> 16);
  float r2 = r1 - __uint_as_float(u1);
  h2 = (ushort)(__float_as_uint(r2) >> 16);
}

// 6-term cross-product MFMA: (A0+A1+A2)(B0+B1+B2) to fp32-class accuracy.
#define MFMA6(acc, A0,A1,A2, B0,B1,B2) do { \
  acc = __builtin_amdgcn_mfma_f32_16x16x32_bf16(A0,B0,acc,0,0,0); \
  acc = __builtin_amdgcn_mfma_f32_16x16x32_bf16(A0,B1,acc,0,0,0); \
  acc = __builtin_amdgcn_mfma_f32_16x16x32_bf16(A1,B0,acc,0,0,0); \
  acc = __builtin_amdgcn_mfma_f32_16x16x32_bf16(A1,B1,acc,0,0,0); \
  acc = __builtin_amdgcn_mfma_f32_16x16x32_bf16(A2,B0,acc,0,0,0); \
  acc = __builtin_amdgcn_mfma_f32_16x16x32_bf16(A0,B2,acc,0,0,0); } while(0)

// ---------------------------------------------------------------------------
// Prep: split W1 (1601x64, zero-pad K to 1632) and W2 (64x64) per head into
// 3 bf16 planes, laid out [head][plane][kstep][n][k32] so a wave's B-fragment
// load (n=lane&15, k=quad*8..+7) is 1 KB fully-coalesced.
// ---------------------------------------------------------------------------
__global__ __launch_bounds__(256, 1) void prep_w(
    const float* __restrict__ Ws1, const float* __restrict__ Wo1,
    const float* __restrict__ Ws2, const float* __restrict__ Wo2,
    ushort* __restrict__ w1s, ushort* __restrict__ w2s)
{
  int idx = blockIdx.x*256 + threadIdx.x;
  if (idx < 2*51*2048){
    int head = idx / (51*2048);
    int rem  = idx % (51*2048);
    int step = rem >> 11;
    int n    = (rem >> 5) & 63;
    int k    = rem & 31;
    int kg   = step*32 + k;
    const float* W = head ? Wo1 : Ws1;
    float v = (kg < NC) ? W[(size_t)kg*HID + n] : 0.f;
    ushort h0,h1,h2; split3(v,h0,h1,h2);
    size_t base = (size_t)head*3*104448 + rem;   // 104448 = 51*2048
    w1s[base]            = h0;
    w1s[base + 104448]   = h1;
    w1s[base + 2*104448] = h2;
  } else {
    int idx2 = idx - 2*51*2048;
    if (idx2 < 2*4096){
      int head = idx2 >> 12;
      int rem  = idx2 & 4095;
      int step = rem >> 11;
      int n    = (rem >> 5) & 63;
      int k    = rem & 31;
      int kg   = step*32 + k;
      const float* W = head ? Wo2 : Ws2;
      float v = W[(size_t)kg*HID + n];
      ushort h0,h1,h2; split3(v,h0,h1,h2);
      size_t base = (size_t)head*3*4096 + rem;
      w2s[base]          = h0;
      w2s[base + 4096]   = h1;
      w2s[base + 2*4096] = h2;
    }
  }
}

// ---------------------------------------------------------------------------
// Kernel A: fused 2-layer MLP on matrix cores (bf16x3, 6-term).
// 64 rows/block, 4 waves; wave w owns m-tile rows w*16..+15, both heads.
// Per K-step(32): stage x fp32 -> 3 LDS bf16 planes (double-buffered),
// A-frag = 1 ds_read_b128/plane; B direct from prepped global (coalesced).
// Layer 2: h -> LDS planes (wave-local, A-layout) -> 2 K-steps MFMA.
// ---------------------------------------------------------------------------
__global__ __launch_bounds__(256) void mlp_mfma(
    const float* __restrict__ x,
    const ushort* __restrict__ w1s, const ushort* __restrict__ w2s,
    const float* __restrict__ bs1, const float* __restrict__ bs2,
    const float* __restrict__ bo1, const float* __restrict__ bo2,
    float* __restrict__ subj, float* __restrict__ obj)
{
  __shared__ __align__(16) ushort xpl[2][3][64*MSTR];   // 30720 B
  const int tid  = threadIdx.x;
  const int lane = tid & 63;
  const int wave = tid >> 6;
  const int col  = lane & 15;
  const int quad = lane >> 4;
  const int row0 = blockIdx.x * 64;

  floatx4 acc[2][4];
  #pragma unroll
  for (int h=0; h<2; h++)
    #pragma unroll
    for (int nt=0; nt<4; nt++) acc[h][nt] = (floatx4){0.f,0.f,0.f,0.f};

  float stg[8];
  #pragma unroll
  for (int it=0; it<8; it++){
    int u = tid + it*256;
    stg[it] = x[(size_t)(row0 + (u>>5))*NC + (u&31)];
  }

  for (int s = 0; s < 51; s++){
    ushort (*xb)[64*MSTR] = xpl[s & 1];
    #pragma unroll
    for (int it=0; it<8; it++){
      int u = tid + it*256;
      int a = (u>>5)*MSTR + (u&31);
      ushort h0,h1,h2; split3(stg[it], h0,h1,h2);
      xb[0][a]=h0; xb[1][a]=h1; xb[2][a]=h2;
    }
    __syncthreads();
    if (s+1 < 51){
      #pragma unroll
      for (int it=0; it<8; it++){
        int u = tid + it*256;
        int kg = (s+1)*32 + (u&31);
        stg[it] = (kg < NC) ? x[(size_t)(row0 + (u>>5))*NC + kg] : 0.f;
      }
    }
    short8 Bf[2][4][3];
    #pragma unroll
    for (int h=0; h<2; h++)
      #pragma unroll
      for (int nt=0; nt<4; nt++)
        #pragma unroll
        for (int p=0; p<3; p++)
          Bf[h][nt][p] = *(const short8*)(w1s +
              (size_t)(((h*3+p)*51 + s)*2048 + nt*512 + col*32 + quad*8));
    short8 Af[3];
    #pragma unroll
    for (int p=0; p<3; p++)
      Af[p] = *(const short8*)&xb[p][(wave*16 + col)*MSTR + quad*8];
    #pragma unroll
    for (int h=0; h<2; h++)
      #pragma unroll
      for (int nt=0; nt<4; nt++)
        MFMA6(acc[h][nt], Af[0],Af[1],Af[2], Bf[h][nt][0],Bf[h][nt][1],Bf[h][nt][2]);
  }
  __syncthreads();   // xpl reused as h-planes (regions overlap across waves)

  ushort* hp = &xpl[0][0][0];   // [3][64*HSTR] = 13824 ushorts, fits in xpl
  #pragma unroll 1
  for (int h=0; h<2; h++){
    const float* b1 = h ? bo1 : bs1;
    const float* b2 = h ? bo2 : bs2;
    float* yout = h ? obj : subj;
    #pragma unroll
    for (int nt=0; nt<4; nt++){
      float bias = b1[nt*16 + col];
      #pragma unroll
      for (int r=0; r<4; r++){
        float hv = fmaxf(acc[h][nt][r] + bias, 0.f);
        ushort h0,h1,h2; split3(hv,h0,h1,h2);
        int a = (wave*16 + quad*4 + r)*HSTR + nt*16 + col;   // wave-local rows
        hp[a] = h0; hp[64*HSTR + a] = h1; hp[2*64*HSTR + a] = h2;
      }
    }
    floatx4 acc2[4];
    #pragma unroll
    for (int nt=0; nt<4; nt++) acc2[nt] = (floatx4){0.f,0.f,0.f,0.f};
    #pragma unroll
    for (int t=0; t<2; t++){
      short8 Af2[3];
      #pragma unroll
      for (int p=0; p<3; p++)
        Af2[p] = *(const short8*)&hp[p*64*HSTR + (wave*16 + col)*HSTR + t*32 + quad*8];
      #pragma unroll
      for (int nt=0; nt<4; nt++){
        short8 Bq[3];
        #pragma unroll
        for (int p=0; p<3; p++)
          Bq[p] = *(const short8*)(w2s +
              (size_t)(((h*3+p)*2 + t)*2048 + nt*512 + col*32 + quad*8));
        MFMA6(acc2[nt], Af2[0],Af2[1],Af2[2], Bq[0],Bq[1],Bq[2]);
      }
    }
    #pragma unroll
    for (int nt=0; nt<4; nt++){
      float bv = b2[nt*16 + col];
      #pragma unroll
      for (int r=0; r<4; r++){
        int gr = row0 + wave*16 + quad*4 + r;
        yout[(size_t)gr*HID + nt*16 + col] = acc2[nt][r] + bv;
      }
    }
  }
}

// ---------------------------------------------------------------------------
// Kernel B0: per-batch sampled FLOOR (fp32; only a lower bound — B1 applies
// an extra 2^16 key margin to absorb fp32-vs-MFMA arithmetic differences).
// ---------------------------------------------------------------------------
__global__ __launch_bounds__(256, 1) void sample_thresh(
    const float* __restrict__ subj, const float* __restrict__ obj,
    uint32_t* __restrict__ L)
{
  __shared__ float sRows[SROWS*HID];
  __shared__ uint32_t keys[SROWS*NN];
  __shared__ uint32_t hist[256];
  __shared__ uint32_t sb[2];
  const int b = blockIdx.x, tid = threadIdx.x;

  const float4* sp = (const float4*)(subj + (size_t)b*NN*HID);
  if (tid < SROWS*16) ((float4*)sRows)[tid] = sp[tid];
  __syncthreads();

  for (int j = tid; j < NN; j += 256){
    const float4* op4 = (const float4*)(obj + ((size_t)b*NN + j)*HID);
    float4 o[16];
    #pragma unroll
    for (int q=0;q<16;q++) o[q] = op4[q];
    #pragma unroll 1
    for (int i=0;i<SROWS;i++){
      const float4* s4 = (const float4*)(sRows + i*HID);
      float acc = 0.f;
      #pragma unroll
      for (int q=0;q<16;q++){
        float4 s = s4[q];
        acc = fmaf(s.x, o[q].x, acc); acc = fmaf(s.y, o[q].y, acc);
        acc = fmaf(s.z, o[q].z, acc); acc = fmaf(s.w, o[q].w, acc);
      }
      keys[i*NN + j] = f2key(acc);
    }
  }
  __syncthreads();

  uint32_t prefix = 0; int remaining = 64;
  for (int round = 0; round < 2; round++){
    const int shift = 24 - round*8;
    hist[tid] = 0;
    __syncthreads();
    for (int idx = tid; idx < SROWS*NN; idx += 256){
      uint32_t k = keys[idx];
      bool match = (round == 0) || ((k >> 24) == (prefix >> 24));
      if (match) atomicAdd(&hist[(k >> shift) & 255u], 1u);
    }
    __syncthreads();
    if (tid == 0){
      uint32_t cum = 0; int bin = 255;
      for (;; bin--){ cum += hist[bin]; if (cum >= (uint32_t)remaining || bin == 0) break; }
      sb[0] = (uint32_t)bin;
      sb[1] = (uint32_t)(remaining - (int)(cum - hist[bin]));
    }
    __syncthreads();
    prefix |= sb[0] << shift;
    remaining = (int)sb[1];
    __syncthreads();
  }
  if (tid == 0) L[b] = prefix;
}

// ---------------------------------------------------------------------------
// Shared MFMA tile for B1/B3: 128x128 scores, K=64 in two 32-chunks.
// subj rows -> A planes, obj rows -> B planes (both [row][k], no transpose).
// Identical instruction stream in B1/B3 -> bitwise-consistent keys.
// ---------------------------------------------------------------------------
__device__ __forceinline__ void score_tile_mfma(
    const float* __restrict__ subj, const float* __restrict__ obj,
    int b, int ti, int tj, int tid,
    ushort* __restrict__ apl, ushort* __restrict__ bpl,
    floatx4 (&acc)[2][8])
{
  const int lane = tid & 63;
  const int wave = tid >> 6;
  const int col  = lane & 15;
  const int quad = lane >> 4;
  #pragma unroll
  for (int mt=0; mt<2; mt++)
    #pragma unroll
    for (int nt=0; nt<8; nt++) acc[mt][nt] = (floatx4){0.f,0.f,0.f,0.f};

  #pragma unroll 1
  for (int half=0; half<2; half++){
    __syncthreads();                       // previous chunk's frag reads done
    #pragma unroll
    for (int it=0; it<4; it++){
      int u = tid + it*256;
      int r = u >> 3, q = u & 7;
      int gr = b*NN + ti + r; gr = gr < ROWS ? gr : (ROWS-1);
      float4 v = ((const float4*)subj)[(size_t)gr*16 + half*8 + q];
      ushort x0,x1,x2,y0,y1,y2,z0,z1,z2,w0,w1,w2;
      split3(v.x,x0,x1,x2); split3(v.y,y0,y1,y2);
      split3(v.z,z0,z1,z2); split3(v.w,w0,w1,w2);
      int a = r*PSTR + q*4;
      *(uint2*)&apl[0*PPL + a] = make_uint2((uint32_t)x0 | ((uint32_t)y0<<16),
                                           (uint32_t)z0 | ((uint32_t)w0<<16));
      *(uint2*)&apl[1*PPL + a] = make_uint2((uint32_t)x1 | ((uint32_t)y1<<16),
                                           (uint32_t)z1 | ((uint32_t)w1<<16));
      *(uint2*)&apl[2*PPL + a] = make_uint2((uint32_t)x2 | ((uint32_t)y2<<16),
                                           (uint32_t)z2 | ((uint32_t)w2<<16));
    }
    #pragma unroll
    for (int it=0; it<4; it++){
      int u = tid + it*256;
      int r = u >> 3, q = u & 7;
      int gr = b*NN + tj + r; gr = gr < ROWS ? gr : (ROWS-1);
      float4 v = ((const float4*)obj)[(size_t)gr*16 + half*8 + q];
      ushort x0,x1,x2,y0,y1,y2,z0,z1,z2,w0,w1,w2;
      split3(v.x,x0,x1,x2); split3(v.y,y0,y1,y2);
      split3(v.z,z0,z1,z2); split3(v.w,w0,w1,w2);
      int a = r*PSTR + q*4;
      *(uint2*)&bpl[0*PPL + a] = make_uint2((uint32_t)x0 | ((uint32_t)y0<<16),
                                           (uint32_t)z0 | ((uint32_t)w0<<16));
      *(uint2*)&bpl[1*PPL + a] = make_uint2((uint32_t)x1 | ((uint32_t)y1<<16),
                                           (uint32_t)z1 | ((uint32_t)w1<<16));
      *(uint2*)&bpl[2*PPL + a] = make_uint2((uint32_t)x2 | ((uint32_t)y2<<16),
                                           (uint32_t)z2 | ((uint32_t)w2<<16));
    }
    __syncthreads();
    short8 Af[2][3];
    #pragma unroll
    for (int mt=0; mt<2; mt++)
      #pragma unroll
      for (int p=0; p<3; p++)
        Af[mt][p] = *(const short8*)&apl[p*PPL + (wave*32 + mt*16 + col)*PSTR + quad*8];
    #pragma unroll
    for (int nt=0; nt<8; nt++){
      short8 Bf[3];
      #pragma unroll
      for (int p=0; p<3; p++)
        Bf[p] = *(const short8*)&bpl[p*PPL + (nt*16 + col)*PSTR + quad*8];
      #pragma unroll
      for (int mt=0; mt<2; mt++)
        MFMA6(acc[mt][nt], Af[mt][0],Af[mt][1],Af[mt][2], Bf[0],Bf[1],Bf[2]);
    }
  }
}

// ---------------------------------------------------------------------------
// Kernel B1: MFMA score tiles; 12-bit histogram of keys >= L[b]-margin +
// candidate append via two-phase reservation.
// ---------------------------------------------------------------------------
__global__ __launch_bounds__(256, 2) void score_pass1(
    const float* __restrict__ subj, const float* __restrict__ obj,
    const uint32_t* __restrict__ L, uint32_t* __restrict__ cnt,
    uint2* __restrict__ cand, uint32_t* __restrict__ ghist)
{
  __shared__ __align__(16) ushort apl[3*PPL];   // 30720 B
  __shared__ __align__(16) ushort bpl[3*PPL];   // 30720 B
  __shared__ uint32_t hist[NBIN];               // 16384 B
  __shared__ uint32_t lcnt, gbase;
  const int blk = blockIdx.x;
  const int b   = blk >> 6;
  const int t   = blk & 63;
  const int ti  = (t >> 3) << 7;
  const int tj  = (t & 7)  << 7;
  const int tid = threadIdx.x;
  const int lane = tid & 63, wave = tid >> 6;
  const int col = lane & 15, quad = lane >> 4;

  for (int i = tid; i < NBIN; i += 256) hist[i] = 0;
  if (tid == 0) lcnt = 0;

  floatx4 acc[2][8];
  score_tile_mfma(subj, obj, b, ti, tj, tid, apl, bpl, acc);

  const uint32_t Lb0 = L[b];
  const uint32_t Lb  = (Lb0 > 65536u) ? (Lb0 - 65536u) : 0u;  // fp32-vs-MFMA margin
  int myCnt = 0;
  #pragma unroll
  for (int mt=0; mt<2; mt++)
    #pragma unroll
    for (int nt=0; nt<8; nt++)
      #pragma unroll
      for (int r=0; r<4; r++){
        int gi = ti + wave*32 + mt*16 + quad*4 + r;
        int gj = tj + nt*16 + col;
        if (gi < NN && gj < NN){
          uint32_t key = f2key(acc[mt][nt][r]);
          if (key >= Lb){ myCnt++; atomicAdd(&hist[key >> 20], 1u); }
        }
      }
  uint32_t lbase = atomicAdd(&lcnt, (uint32_t)myCnt);
  __syncthreads();
  if (tid == 0) gbase = atomicAdd(&cnt[b], lcnt);
  __syncthreads();
  uint32_t pos = gbase + lbase;
  #pragma unroll
  for (int mt=0; mt<2; mt++)
    #pragma unroll
    for (int nt=0; nt<8; nt++)
      #pragma unroll
      for (int r=0; r<4; r++){
        int gi = ti + wave*32 + mt*16 + quad*4 + r;
        int gj = tj + nt*16 + col;
        if (gi < NN && gj < NN){
          uint32_t key = f2key(acc[mt][nt][r]);
          if (key >= Lb){
            if (pos < CAPB) cand[(size_t)b*CAPB + pos] = make_uint2(key, (uint32_t)(gi*NN + gj));
            pos++;
          }
        }
      }
  __syncthreads();
  for (int i = tid; i < NBIN; i += 256){
    uint32_t v = hist[i];
    if (v) atomicAdd(&ghist[(size_t)b*NBIN + i], v);
  }
}

// ---------------------------------------------------------------------------
// Kernel B2: exact 12-bit bucket floor T[b] of the 64th-largest key;
// flag[b] = candidate overflow.
// ---------------------------------------------------------------------------
__global__ __launch_bounds__(256, 1) void pick_thresh(
    const uint32_t* __restrict__ ghist, const uint32_t* __restrict__ cnt,
    uint32_t* __restrict__ T, uint32_t* __restrict__ flag)
{
  __shared__ uint32_t S[256];
  const int b = blockIdx.x, tid = threadIdx.x;
  const uint32_t* h = ghist + (size_t)b*NBIN;
  uint32_t loc[16];
  uint32_t s = 0;
  #pragma unroll
  for (int i=0;i<16;i++){ loc[i] = h[tid*16 + i]; s += loc[i]; }
  S[tid] = s;
  __syncthreads();
  for (int off = 1; off < 256; off <<= 1){
    uint32_t v = (tid + off < 256) ? S[tid + off] : 0u;
    __syncthreads();
    S[tid] += v;
    __syncthreads();
  }
  uint32_t above = (tid < 255) ? S[tid + 1] : 0u;
  if (above < 64u && S[tid] >= 64u){
    uint32_t suf = above; int best = 0;
    for (int i=15;i>=0;i--){ suf += loc[i]; if (suf >= 64u){ best = i; break; } }
    T[b] = (uint32_t)(tid*16 + best) << 20;
  }
  if (tid == 0) flag[b] = (cnt[b] > (uint32_t)CAPB) ? 1u : 0u;
}

// ---------------------------------------------------------------------------
// Kernel B3: repair pass for overflowed batches (early-exit common case).
// Same MFMA tile fn as B1 -> identical keys.
// ---------------------------------------------------------------------------
__global__ __launch_bounds__(256, 2) void score_repair(
    const float* __restrict__ subj, const float* __restrict__ obj,
    const uint32_t* __restrict__ T, const uint32_t* __restrict__ flag,
    uint32_t* __restrict__ cnt2, uint2* __restrict__ cand)
{
  const int blk = blockIdx.x;
  const int b   = blk >> 6;
  if (flag[b] == 0u) return;

  __shared__ __align__(16) ushort apl[3*PPL];
  __shared__ __align__(16) ushort bpl[3*PPL];
  __shared__ uint32_t lcnt, gbase;
  const int t   = blk & 63;
  const int ti  = (t >> 3) << 7;
  const int tj  = (t & 7)  << 7;
  const int tid = threadIdx.x;
  const int lane = tid & 63, wave = tid >> 6;
  const int col = lane & 15, quad = lane >> 4;

  if (tid == 0) lcnt = 0;

  floatx4 acc[2][8];
  score_tile_mfma(subj, obj, b, ti, tj, tid, apl, bpl, acc);

  const uint32_t Tb = T[b];
  int myCnt = 0;
  #pragma unroll
  for (int mt=0; mt<2; mt++)
    #pragma unroll
    for (int nt=0; nt<8; nt++)
      #pragma unroll
      for (int r=0; r<4; r++){
        int gi = ti + wave*32 + mt*16 + quad*4 + r;
        int gj = tj + nt*16 + col;
        if (gi < NN && gj < NN && f2key(acc[mt][nt][r]) >= Tb) myCnt++;
      }
  uint32_t lbase = atomicAdd(&lcnt, (uint32_t)myCnt);
  __syncthreads();
  if (tid == 0) gbase = atomicAdd(&cnt2[b], lcnt);
  __syncthreads();
  uint32_t pos = gbase + lbase;
  #pragma unroll
  for (int mt=0; mt<2; mt++)
    #pragma unroll
    for (int nt=0; nt<8; nt++)
      #pragma unroll
      for (int r=0; r<4; r++){
        int gi = ti + wave*32 + mt*16 + quad*4 + r;
        int gj = tj + nt*16 + col;
        if (gi < NN && gj < NN){
          uint32_t key = f2key(acc[mt][nt][r]);
          if (key >= Tb){
            if (pos < CAPB) cand[(size_t)b*CAPB + pos] = make_uint2(key, (uint32_t)(gi*NN + gj));
            pos++;
          }
        }
      }
}

// ---------------------------------------------------------------------------
// Kernel C: exact top-64 per batch. Radix-select 64th key, rank by
// (value desc, index asc) = jax.lax.top_k tie semantics.
// ---------------------------------------------------------------------------
__global__ __launch_bounds__(256, 1) void final_select(
    const uint32_t* __restrict__ cnt, const uint32_t* __restrict__ cnt2,
    const uint32_t* __restrict__ flag, const uint2* __restrict__ cand,
    float* __restrict__ out)
{
  __shared__ uint32_t keys[CAPB];
  __shared__ uint32_t hist[256];
  __shared__ uint32_t sb[2];
  __shared__ uint2 win[192];
  __shared__ uint32_t wn;
  const int b = blockIdx.x, tid = threadIdx.x;
  uint32_t n0 = flag[b] ? cnt2[b] : cnt[b];
  const int n = (n0 < (uint32_t)CAPB) ? (int)n0 : CAPB;

  for (int i = tid; i < n; i += 256) keys[i] = cand[(size_t)b*CAPB + i].x;
  if (tid == 0) wn = 0;
  __syncthreads();

  uint32_t prefix = 0; int remaining = 64;
  for (int round = 0; round < 4; round++){
    const int shift = 24 - round*8;
    hist[tid] = 0;
    __syncthreads();
    for (int i = tid; i < n; i += 256){
      uint32_t k = keys[i];
      bool match = (round == 0) || ((k >> (shift+8)) == (prefix >> (shift+8)));
      if (match) atomicAdd(&hist[(k >> shift) & 255u], 1u);
    }
    __syncthreads();
    if (tid == 0){
      uint32_t cum = 0; int bin = 255;
      for (;; bin--){ cum += hist[bin]; if (cum >= (uint32_t)remaining || bin == 0) break; }
      sb[0] = (uint32_t)bin;
      sb[1] = (uint32_t)(remaining - (int)(cum - hist[bin]));
    }
    __syncthreads();
    prefix |= sb[0] << shift;
    remaining = (int)sb[1];
    __syncthreads();
  }
  const uint32_t Tk = prefix;

  for (int i = tid; i < n; i += 256){
    if (keys[i] >= Tk){
      uint32_t p = atomicAdd(&wn, 1u);
      if (p < 192u) win[p] = make_uint2(keys[i], cand[(size_t)b*CAPB + i].y);
    }
  }
  __syncthreads();
  const int m = (wn < 192u) ? (int)wn : 192;

  if (tid < m){
    const uint64_t me = ((uint64_t)win[tid].x << 32) | (uint64_t)(uint32_t)(~win[tid].y);
    int rank = 0;
    for (int s = 0; s < m; s++){
      uint64_t oth = ((uint64_t)win[s].x << 32) | (uint64_t)(uint32_t)(~win[s].y);
      rank += (oth > me) ? 1 : 0;
    }
    if (rank < 64){
      const uint32_t f = win[tid].y;
      const float d  = key2f(win[tid].x);
      const float sc = 1.0f / (1.0f + expf(-d));
      out[((size_t)b*64 + rank)*2 + 0] = (float)(f / NN);
      out[((size_t)b*64 + rank)*2 + 1] = (float)(f % NN);
      out[(size_t)NB*64*2 + (size_t)b*64 + rank] = sc;
    }
  }
}

// ---------------------------------------------------------------------------
extern "C" void kernel_launch(void* const* d_in, const int* in_sizes, int n_in,
                              void* d_out, int out_size, void* d_ws, size_t ws_size,
                              hipStream_t stream) {
  const float* x   = (const float*)d_in[0];
  const float* Ws1 = (const float*)d_in[2];
  const float* bs1 = (const float*)d_in[3];
  const float* Ws2 = (const float*)d_in[4];
  const float* bs2 = (const float*)d_in[5];
  const float* Wo1 = (const float*)d_in[6];
  const float* bo1 = (const float*)d_in[7];
  const float* Wo2 = (const float*)d_in[8];
  const float* bo2 = (const float*)d_in[9];
  float* out = (float*)d_out;

  char* ws = (char*)d_ws;
  float*    subj = (float*)ws;                        //  8,192,000 B
  float*    objp = (float*)(ws + 8192000);            //  8,192,000 B
  uint32_t* L    = (uint32_t*)(ws + 16384000);        //        128 B
  uint32_t* cnt  = (uint32_t*)(ws + 16384128);        //        128 B
  uint32_t* cnt2 = (uint32_t*)(ws + 16384256);        //        128 B
  uint32_t* ghist= (uint32_t*)(ws + 16384384);        //    524,288 B
  uint32_t* T    = (uint32_t*)(ws + 16908672);        //        128 B
  uint32_t* flag = (uint32_t*)(ws + 16908800);        //        128 B
  uint2*    cand = (uint2*)   (ws + 16908928);        //  3,932,160 B
  ushort*   w1s  = (ushort*)  (ws + 20841088);        //  1,253,376 B
  ushort*   w2s  = (ushort*)  (ws + 22094464);        //     49,152 B (22.1 MB total)

  hipMemsetAsync(cnt, 0, 128 + 128 + 524288, stream);

  prep_w<<<848, 256, 0, stream>>>(Ws1, Wo1, Ws2, Wo2, w1s, w2s);
  mlp_mfma<<<ROWS/64, 256, 0, stream>>>(x, w1s, w2s, bs1, bs2, bo1, bo2, subj, objp);
  sample_thresh<<<NB, 256, 0, stream>>>(subj, objp, L);
  score_pass1<<<NB*64, 256, 0, stream>>>(subj, objp, L, cnt, cand, ghist);
  pick_thresh<<<NB, 256, 0, stream>>>(ghist, cnt, T, flag);
  score_repair<<<NB*64, 256, 0, stream>>>(subj, objp, T, flag, cnt2, cand);
  final_select<<<NB, 256, 0, stream>>>(cnt, cnt2, flag, cand, out);
}